// Round 16
// baseline (3375.742 us; speedup 1.0000x reference)
//
#include <hip/hip_runtime.h>

#define NBLK  256
#define NTHR  384
#define TDEC  128
#define TENC  256
#define DIN   256
#define DENC  512
#define HHH   512
#define NG    1536
#define KTOT  1280
#define NK4   320
#define ASTR  516          // padded [b][k] row stride in floats
#define ASTR4 129          // in float4

// ws layout: flag bytes first, then float arrays. Offsets in floats.
#define FLAGS_BYTES (128*3*16*16)         // [t][event][bg][cg-byte] = 98304 B
#define OFF_U     24576
#define OFF_ECTX  25600
#define OFF_HG    41984
#define OFF_CTXG  74752
#define OFF_RHG   107520
#define OFF_HD    140288                  // [bg][cg][b] 1024 floats (single-buffered)
#define OFF_WP    141312                  // 16*320*96*4 = 1,966,080 elems
#define WP_ELEMS  (16*NK4*96*4)
// end = 2,107,392 floats = 8.43 MB

// ---------------- small helpers ----------------
__device__ __forceinline__ float wave_sum(float v) {
#pragma unroll
    for (int o = 32; o; o >>= 1) v += __shfl_down(v, o, 64);
    return v;
}
__device__ __forceinline__ float wave_max(float v) {
#pragma unroll
    for (int o = 32; o; o >>= 1) v = fmaxf(v, __shfl_down(v, o, 64));
    return v;
}
__device__ __forceinline__ void stA(float* p, float v) {
    __hip_atomic_store(p, v, __ATOMIC_RELAXED, __HIP_MEMORY_SCOPE_AGENT);
}
__device__ __forceinline__ float ldAf(float* p) {
    return __hip_atomic_load(p, __ATOMIC_RELAXED, __HIP_MEMORY_SCOPE_AGENT);
}
// 64-bit relaxed agent-scope load (2 floats per issue)
__device__ __forceinline__ float2 ldA2(float* p) {
    double d = __hip_atomic_load((double*)p, __ATOMIC_RELAXED, __HIP_MEMORY_SCOPE_AGENT);
    return *(float2*)&d;
}
__device__ __forceinline__ void drain_stores() {
    asm volatile("s_waitcnt vmcnt(0)" ::: "memory");
}
__device__ __forceinline__ void setflag(unsigned char* p) {
    __hip_atomic_store(p, (unsigned char)1, __ATOMIC_RELAXED, __HIP_MEMORY_SCOPE_AGENT);
}
__device__ __forceinline__ void waitflags16(unsigned* f) {
    for (;;) {
        unsigned a0 = __hip_atomic_load(f + 0, __ATOMIC_RELAXED, __HIP_MEMORY_SCOPE_AGENT);
        unsigned a1 = __hip_atomic_load(f + 1, __ATOMIC_RELAXED, __HIP_MEMORY_SCOPE_AGENT);
        unsigned a2 = __hip_atomic_load(f + 2, __ATOMIC_RELAXED, __HIP_MEMORY_SCOPE_AGENT);
        unsigned a3 = __hip_atomic_load(f + 3, __ATOMIC_RELAXED, __HIP_MEMORY_SCOPE_AGENT);
        if ((a0 & a1 & a2 & a3) == 0x01010101u) return;
    }
}
__device__ __forceinline__ float blo(unsigned u) { return __uint_as_float(u << 16); }
__device__ __forceinline__ float bhi(unsigned u) { return __uint_as_float(u & 0xffff0000u); }
__device__ __forceinline__ unsigned short f2bf(float f) {
    unsigned u = __float_as_uint(f);
    u += 0x7fffu + ((u >> 16) & 1u);
    return (unsigned short)(u >> 16);
}

// 4-batch dot: thread owns ONE col (kcol) and a k4 range; one weight float4 load
// feeds 4 batches (acc.x..acc.w = batches 0..3). Activation reads are wave-broadcast.
template<bool BF>
__device__ __forceinline__ float4 dotq(const void* wp, int cg, int kcol,
                                       int k4lo, int k4hi, const float* abase,
                                       int aoff, float4 acc) {
    if (BF) {
        const uint2* w = (const uint2*)wp + (size_t)cg*NK4*96 + kcol;
#pragma unroll 4
        for (int k4 = k4lo; k4 < k4hi; ++k4) {
            uint2 uu = w[(size_t)k4 * 96];
            float wx = blo(uu.x), wy = bhi(uu.x), wz = blo(uu.y), ww = bhi(uu.y);
            const float* ao = abase + (k4 - aoff)*4;
            float4 A0 = *(const float4*)(ao + 0*ASTR);
            float4 A1 = *(const float4*)(ao + 1*ASTR);
            float4 A2 = *(const float4*)(ao + 2*ASTR);
            float4 A3 = *(const float4*)(ao + 3*ASTR);
            acc.x = fmaf(wx, A0.x, acc.x); acc.x = fmaf(wy, A0.y, acc.x);
            acc.x = fmaf(wz, A0.z, acc.x); acc.x = fmaf(ww, A0.w, acc.x);
            acc.y = fmaf(wx, A1.x, acc.y); acc.y = fmaf(wy, A1.y, acc.y);
            acc.y = fmaf(wz, A1.z, acc.y); acc.y = fmaf(ww, A1.w, acc.y);
            acc.z = fmaf(wx, A2.x, acc.z); acc.z = fmaf(wy, A2.y, acc.z);
            acc.z = fmaf(wz, A2.z, acc.z); acc.z = fmaf(ww, A2.w, acc.z);
            acc.w = fmaf(wx, A3.x, acc.w); acc.w = fmaf(wy, A3.y, acc.w);
            acc.w = fmaf(wz, A3.z, acc.w); acc.w = fmaf(ww, A3.w, acc.w);
        }
    } else {
        const float4* w = (const float4*)wp + (size_t)cg*NK4*96 + kcol;
#pragma unroll 4
        for (int k4 = k4lo; k4 < k4hi; ++k4) {
            float4 wv = w[(size_t)k4 * 96];
            const float* ao = abase + (k4 - aoff)*4;
            float4 A0 = *(const float4*)(ao + 0*ASTR);
            float4 A1 = *(const float4*)(ao + 1*ASTR);
            float4 A2 = *(const float4*)(ao + 2*ASTR);
            float4 A3 = *(const float4*)(ao + 3*ASTR);
            acc.x = fmaf(wv.x, A0.x, acc.x); acc.x = fmaf(wv.y, A0.y, acc.x);
            acc.x = fmaf(wv.z, A0.z, acc.x); acc.x = fmaf(wv.w, A0.w, acc.x);
            acc.y = fmaf(wv.x, A1.x, acc.y); acc.y = fmaf(wv.y, A1.y, acc.y);
            acc.y = fmaf(wv.z, A1.z, acc.y); acc.y = fmaf(wv.w, A1.w, acc.y);
            acc.z = fmaf(wv.x, A2.x, acc.z); acc.z = fmaf(wv.y, A2.y, acc.z);
            acc.z = fmaf(wv.z, A2.z, acc.z); acc.z = fmaf(wv.w, A2.w, acc.z);
            acc.w = fmaf(wv.x, A3.x, acc.w); acc.w = fmaf(wv.y, A3.y, acc.w);
            acc.w = fmaf(wv.z, A3.z, acc.w); acc.w = fmaf(wv.w, A3.w, acc.w);
        }
    }
    return acc;
}

// ---------------- precompute kernels (unchanged) ----------------
__global__ void k_u(const float* __restrict__ w1, const float* __restrict__ w2,
                    float* __restrict__ u) {
    int e = blockIdx.x;
    int lane = threadIdx.x;
    float p = 0.f;
#pragma unroll
    for (int k = lane; k < DENC; k += 64) p += w1[e*DENC + k] * w2[k];
    p = wave_sum(p);
    if (lane == 0) u[e] = p;
}

__global__ void k_ectx(const float* __restrict__ C, const float* __restrict__ u,
                       float* __restrict__ ectx) {
    int r = blockIdx.x*4 + (threadIdx.x >> 6);
    int lane = threadIdx.x & 63;
    const float* row = C + (size_t)r*DENC;
    const float* vc  = u + HHH;
    float p = 0.f;
#pragma unroll
    for (int k = 0; k < DENC/64; ++k) p += row[lane + k*64] * vc[lane + k*64];
    p = wave_sum(p);
    if (lane == 0) ectx[r] = p;
}

template<bool BF>
__global__ void k_wpack(const float* __restrict__ Wx, const float* __restrict__ Wh,
                        void* __restrict__ wp) {
    int id = blockIdx.x*256 + threadIdx.x;
    int e = id & 3;
    int q = id >> 2;
    int col = q % 96;
    q /= 96;
    int k4 = q % NK4;
    int cg = q / NK4;
    int k = k4*4 + e;
    int j = (col >> 5)*512 + cg*32 + (col & 31);
    float v = (k < 768) ? Wx[(size_t)k*NG + j] : Wh[(size_t)(k-768)*NG + j];
    if (BF) ((unsigned short*)wp)[id] = f2bf(v);
    else    ((float*)wp)[id] = v;
}

// ---------------- main kernel ----------------
// 256 blocks = (bg = blk>>4) x (cg = blk&15): 4 batches x 96 cols (32 z, 32 r, 32 h).
// Attention role: b_att = blk>>2, ds = blk&3. Dot threads: ks=tid/96, kcol=tid%96.
template<bool BF>
__launch_bounds__(NTHR, 1)
__global__ void decoder(const float* __restrict__ inp, const float* __restrict__ C,
                        const float* __restrict__ bias, const void* __restrict__ wpv,
                        const float* __restrict__ u, float* __restrict__ ectx_g,
                        float* __restrict__ out, float* __restrict__ ws) {
    unsigned char* fl = (unsigned char*)ws;
    float* hG   = ws + OFF_HG;
    float* ctxG = ws + OFF_CTXG;
    float* rhG  = ws + OFF_RHG;
    float* hdP  = ws + OFF_HD;

    const int tid  = threadIdx.x;
    const int w    = tid >> 6;
    const int blk  = blockIdx.x;
    const int bg   = blk >> 4;
    const int cg   = blk & 15;
    const int b_att = blk >> 2;
    const int ds    = blk & 3;
    const int bl_att = cg >> 2;        // == b_att & 3
    const int ks   = tid / 96;
    const int kcol = tid - ks*96;
    const int sub  = kcol >> 5;
    const int q32k = kcol & 31;
    const int jpk  = cg*32 + q32k;

    __shared__ float sh_C[TENC*128];                 // 131 KB fp32 C slice [q][dp]
    __shared__ __align__(16) float sh_st[4*ASTR];    // staging [b][k]: x -> ctx -> rh
    __shared__ __align__(16) float sh_h[4*ASTR];     // h_prev [b][k]
    __shared__ __align__(16) float sh_part[1536];    // [ks][col][b] K-split partials
    __shared__ float sh_att[TENC];
    __shared__ float sh_ectx[TENC];
    __shared__ __align__(16) float sh_u[512];
    __shared__ float sh_z[128];                      // [q32][b]
    __shared__ float sh_cred[2][128];
    __shared__ float sh_red[4];
    __shared__ float sh_hdp[8];
    __shared__ float sh_scal;

    // one-time staging
    for (int i = tid; i < TENC*128; i += NTHR)
        sh_C[i] = C[((size_t)b_att*TENC + (i >> 7))*DENC + ds*128 + (i & 127)];
    if (tid < TENC) sh_ectx[tid] = ectx_g[b_att*TENC + tid];
    if (tid < 128) ((float4*)sh_u)[tid] = ((const float4*)(u))[tid];
    const float bias_c = bias[sub*512 + jpk];

    const int i0 = tid, i1 = tid + 384, i2 = tid + 768;

    for (int t = 0; t < TDEC; ++t) {
        // ----- stage x (4 batches), float4 coalesced -----
        __syncthreads();                                    // guard sh_st reuse
        if (tid < 256) {
            int bb = tid >> 6, k4i = tid & 63;
            *(float4*)&sh_st[bb*ASTR + k4i*4] =
                *(const float4*)&inp[((size_t)(bg*4 + bb)*TDEC + t)*DIN + k4i*4];
        }
        __syncthreads();

        // ----- x-part dots: k4 quarter of [0,64), all cols, 4 batches -----
        float4 acc = make_float4(ks == 0 ? bias_c : 0.f, ks == 0 ? bias_c : 0.f,
                                 ks == 0 ? bias_c : 0.f, ks == 0 ? bias_c : 0.f);
        acc = dotq<BF>(wpv, cg, kcol, ks*16, ks*16 + 16, sh_st, 0, acc);

        // ----- waitC(t-1) -----
        if (t > 0) {
            if (tid == 0) waitflags16((unsigned*)(fl + ((((t-1)*3 + 2)*16 + bg) << 4)));
            __syncthreads();
        }

        // ----- issue h_prev loads into registers (latency hides under softmax/ctx) -----
        float2 h0, h1, h2;
        if (t > 0) {
            h0 = ldA2(&hG[(size_t)(bg*4 + (i0 >> 8))*HHH + (i0 & 255)*2]);
            h1 = ldA2(&hG[(size_t)(bg*4 + (i1 >> 8))*HHH + (i1 & 255)*2]);
            if (i2 < 1024)
                h2 = ldA2(&hG[(size_t)(bg*4 + (i2 >> 8))*HHH + (i2 & 255)*2]);
        }

        // ----- hd from published partials (wave 0 gathers 16) -----
        if (t > 0) {
            if (tid < 64) {
                float v = (tid < 16) ? ldAf(&hdP[(bg*16 + tid)*4 + bl_att]) : 0.f;
                v += __shfl_xor(v, 1, 64);
                v += __shfl_xor(v, 2, 64);
                v += __shfl_xor(v, 4, 64);
                v += __shfl_xor(v, 8, 64);
                if (tid == 0) sh_scal = v;
            }
        } else if (tid == 0) sh_scal = 0.f;
        __syncthreads();
        const float hd = sh_scal;

        // ----- attention softmax (threads 0..255, matched barriers) -----
        if (tid < TENC) {
            float e = fmaxf(hd + sh_ectx[tid], 0.f);
            float wm = wave_max(e);
            if ((tid & 63) == 0) sh_red[w] = wm;
            __syncthreads();
            float mx = fmaxf(fmaxf(sh_red[0], sh_red[1]), fmaxf(sh_red[2], sh_red[3]));
            float ex = __expf(e - mx);
            float wse = wave_sum(ex);
            __syncthreads();
            if ((tid & 63) == 0) sh_red[w] = wse;
            __syncthreads();
            float dn = sh_red[0] + sh_red[1] + sh_red[2] + sh_red[3];
            sh_att[tid] = ex / dn;
        } else {
            __syncthreads(); __syncthreads(); __syncthreads();
        }
        __syncthreads();

        // ----- ctx slice (b_att, ds) from LDS C; publish early -----
        if (tid < TENC) {
            const int dp = tid & 127, hf = tid >> 7;
            const float* Cl = sh_C + (size_t)hf*128*128 + dp;
            float a = 0.f;
#pragma unroll 8
            for (int q = 0; q < 128; ++q)
                a = fmaf(sh_att[hf*128 + q], Cl[(size_t)q*128], a);
            sh_cred[hf][dp] = a;
        }
        __syncthreads();
        if (tid < 128) stA(&ctxG[(size_t)b_att*HHH + ds*128 + tid],
                           sh_cred[0][tid] + sh_cred[1][tid]);
        drain_stores();
        __syncthreads();
        if (tid == 0) setflag(fl + (((t*3 + 0)*16 + bg) << 4) + cg);   // event A

        // ----- commit h_prev registers to LDS -----
        if (t > 0) {
            *(float2*)&sh_h[(i0 >> 8)*ASTR + (i0 & 255)*2] = h0;
            *(float2*)&sh_h[(i1 >> 8)*ASTR + (i1 & 255)*2] = h1;
            if (i2 < 1024) *(float2*)&sh_h[(i2 >> 8)*ASTR + (i2 & 255)*2] = h2;
        } else {
            for (int i = tid; i < 1024; i += NTHR)
                *(float2*)&sh_h[(i >> 8)*ASTR + (i & 255)*2] = make_float2(0.f, 0.f);
        }
        __syncthreads();

        // ----- h-part dots half 1 (z,r cols): k4 [192+ks*32, +16) -----
        if (t > 0 && kcol < 64)
            acc = dotq<BF>(wpv, cg, kcol, 192 + ks*32, 192 + ks*32 + 16, sh_h, 192, acc);

        // ----- wait A; issue ctx loads; h-dots half 2 over in-flight loads -----
        if (tid == 0) waitflags16((unsigned*)(fl + (((t*3 + 0)*16 + bg) << 4)));
        __syncthreads();
        float2 c0, c1, c2;
        c0 = ldA2(&ctxG[(size_t)(bg*4 + (i0 >> 8))*HHH + (i0 & 255)*2]);
        c1 = ldA2(&ctxG[(size_t)(bg*4 + (i1 >> 8))*HHH + (i1 & 255)*2]);
        if (i2 < 1024)
            c2 = ldA2(&ctxG[(size_t)(bg*4 + (i2 >> 8))*HHH + (i2 & 255)*2]);
        if (t > 0 && kcol < 64)
            acc = dotq<BF>(wpv, cg, kcol, 192 + ks*32 + 16, 192 + ks*32 + 32, sh_h, 192, acc);
        *(float2*)&sh_st[(i0 >> 8)*ASTR + (i0 & 255)*2] = c0;
        *(float2*)&sh_st[(i1 >> 8)*ASTR + (i1 & 255)*2] = c1;
        if (i2 < 1024) *(float2*)&sh_st[(i2 >> 8)*ASTR + (i2 & 255)*2] = c2;
        __syncthreads();

        // ----- ctx dots quarter of [64,192) -----
        acc = dotq<BF>(wpv, cg, kcol, 64 + ks*32, 64 + ks*32 + 32, sh_st, 64, acc);

        // ----- K-split merge for z/r; finish gates; publish rh -----
        __syncthreads();
        if (kcol < 64) *(float4*)&sh_part[tid*4] = acc;     // [(ks*96+kcol)*4]
        __syncthreads();
        if (tid < 256) {
            int cz = tid >> 2, b = tid & 3;
            float s = sh_part[0*384 + cz*4 + b] + sh_part[1*384 + cz*4 + b]
                    + sh_part[2*384 + cz*4 + b] + sh_part[3*384 + cz*4 + b];
            if (cz < 32) {
                sh_z[cz*4 + b] = 1.f / (1.f + __expf(-s));
            } else {
                int jp = cg*32 + (cz - 32);
                float r = 1.f / (1.f + __expf(-s));
                stA(&rhG[(size_t)(bg*4 + b)*HHH + jp], r * sh_h[b*ASTR + jp]);
            }
        }
        drain_stores();
        __syncthreads();
        if (tid == 0) setflag(fl + (((t*3 + 1)*16 + bg) << 4) + cg);   // event B

        // ----- wait B; stage rh; rh dots (h cols); finish h -----
        if (tid == 0) waitflags16((unsigned*)(fl + (((t*3 + 1)*16 + bg) << 4)));
        __syncthreads();
        for (int i = tid; i < 1024; i += NTHR) {
            int bb = i >> 8, j2 = (i & 255)*2;
            float2 f = ldA2(&rhG[(size_t)(bg*4 + bb)*HHH + j2]);
            *(float2*)&sh_st[bb*ASTR + j2] = f;
        }
        __syncthreads();
        if (kcol >= 64) {
            acc = dotq<BF>(wpv, cg, kcol, 192 + ks*32, 192 + ks*32 + 32, sh_st, 192, acc);
            *(float4*)&sh_part[(ks*96 + kcol)*4] = acc;
        }
        __syncthreads();
        if (tid < 128) {
            int q32 = tid >> 2, b = tid & 3;
            int ch = 64 + q32;
            float s = sh_part[0*384 + ch*4 + b] + sh_part[1*384 + ch*4 + b]
                    + sh_part[2*384 + ch*4 + b] + sh_part[3*384 + ch*4 + b];
            int jp = cg*32 + q32;
            float hh = tanhf(s);
            float z  = sh_z[q32*4 + b];
            float hp = sh_h[b*ASTR + jp];
            float hn = z*hp + (1.f - z)*hh;
            stA(&hG[(size_t)(bg*4 + b)*HHH + jp], hn);
            out[((size_t)(bg*4 + b)*TDEC + t)*HHH + jp] = hn;
            // hdot partial: sum over q32 within wave (lanes differ in bits 2..5)
            float p = sh_u[jp] * hn;
            p += __shfl_xor(p, 4, 64);
            p += __shfl_xor(p, 8, 64);
            p += __shfl_xor(p, 16, 64);
            p += __shfl_xor(p, 32, 64);
            if ((tid & 63) < 4) sh_hdp[(tid >> 6)*4 + (tid & 3)] = p;
        }
        __syncthreads();
        if (tid < 4) stA(&hdP[(bg*16 + cg)*4 + tid], sh_hdp[tid] + sh_hdp[4 + tid]);
        drain_stores();
        __syncthreads();
        if (tid == 0) setflag(fl + (((t*3 + 2)*16 + bg) << 4) + cg);   // event C
    }
}

extern "C" void kernel_launch(void* const* d_in, const int* in_sizes, int n_in,
                              void* d_out, int out_size, void* d_ws, size_t ws_size,
                              hipStream_t stream) {
    const float* inputs = (const float*)d_in[0];
    const float* C      = (const float*)d_in[1];
    const float* w1     = (const float*)d_in[2];
    const float* w2     = (const float*)d_in[3];
    const float* Wx     = (const float*)d_in[4];
    const float* Wh     = (const float*)d_in[5];
    const float* bias   = (const float*)d_in[6];
    float* out = (float*)d_out;
    float* ws  = (float*)d_ws;

    hipMemsetAsync(ws, 0, FLAGS_BYTES, stream);

    k_u   <<<1024, 64,  0, stream>>>(w1, w2, ws + OFF_U);
    k_ectx<<<(64*TENC)/4, 256, 0, stream>>>(C, ws + OFF_U, ws + OFF_ECTX);

    const size_t need_f32 = (size_t)(OFF_WP) * 4u + (size_t)WP_ELEMS * 4u;
    void* wp = (void*)(ws + OFF_WP);
    if (ws_size >= need_f32) {
        k_wpack<false><<<WP_ELEMS/256, 256, 0, stream>>>(Wx, Wh, wp);
        decoder<false><<<NBLK, NTHR, 0, stream>>>(inputs, C, bias, wp,
                                                  ws + OFF_U, ws + OFF_ECTX, out, ws);
    } else {
        k_wpack<true><<<WP_ELEMS/256, 256, 0, stream>>>(Wx, Wh, wp);
        decoder<true><<<NBLK, NTHR, 0, stream>>>(inputs, C, bias, wp,
                                                 ws + OFF_U, ws + OFF_ECTX, out, ws);
    }
}

// Round 17
// 2870.668 us; speedup vs baseline: 1.1759x; 1.1759x over previous
//
#include <hip/hip_runtime.h>

#define NBLK  256
#define NTHR  384
#define TDEC  128
#define TENC  256
#define DIN   256
#define DENC  512
#define HHH   512
#define NG    1536
#define KTOT  1280
#define NK4   320
#define ASTR  516          // padded [b][k] row stride in floats
#define ASTR4 129          // in float4

// ws layout: flag bytes first, then float arrays. Offsets in floats.
#define FLAGS_BYTES (128*3*16*16)         // [t][event][bg][cg-byte] = 98304 B
#define OFF_U     24576
#define OFF_ECTX  25600
#define OFF_HG    41984
#define OFF_CTXG  74752
#define OFF_RHG   107520
#define OFF_HD    140288                  // [bg][cg][b] 1024 floats (single-buffered)
#define OFF_WP    141312                  // 16*320*96*4 = 1,966,080 elems
#define WP_ELEMS  (16*NK4*96*4)
// end = 2,107,392 floats = 8.43 MB

// ---------------- small helpers ----------------
__device__ __forceinline__ float wave_sum(float v) {
#pragma unroll
    for (int o = 32; o; o >>= 1) v += __shfl_down(v, o, 64);
    return v;
}
__device__ __forceinline__ float wave_max(float v) {
#pragma unroll
    for (int o = 32; o; o >>= 1) v = fmaxf(v, __shfl_down(v, o, 64));
    return v;
}
__device__ __forceinline__ void stA(float* p, float v) {
    __hip_atomic_store(p, v, __ATOMIC_RELAXED, __HIP_MEMORY_SCOPE_AGENT);
}
__device__ __forceinline__ float ldAf(float* p) {
    return __hip_atomic_load(p, __ATOMIC_RELAXED, __HIP_MEMORY_SCOPE_AGENT);
}
// 64-bit relaxed agent-scope load (2 floats per issue)
__device__ __forceinline__ float2 ldA2(float* p) {
    double d = __hip_atomic_load((double*)p, __ATOMIC_RELAXED, __HIP_MEMORY_SCOPE_AGENT);
    return *(float2*)&d;
}
__device__ __forceinline__ void drain_stores() {
    asm volatile("s_waitcnt vmcnt(0)" ::: "memory");
}
__device__ __forceinline__ void setflag(unsigned char* p) {
    __hip_atomic_store(p, (unsigned char)1, __ATOMIC_RELAXED, __HIP_MEMORY_SCOPE_AGENT);
}
__device__ __forceinline__ void waitflags16(unsigned* f) {
    for (;;) {
        unsigned a0 = __hip_atomic_load(f + 0, __ATOMIC_RELAXED, __HIP_MEMORY_SCOPE_AGENT);
        unsigned a1 = __hip_atomic_load(f + 1, __ATOMIC_RELAXED, __HIP_MEMORY_SCOPE_AGENT);
        unsigned a2 = __hip_atomic_load(f + 2, __ATOMIC_RELAXED, __HIP_MEMORY_SCOPE_AGENT);
        unsigned a3 = __hip_atomic_load(f + 3, __ATOMIC_RELAXED, __HIP_MEMORY_SCOPE_AGENT);
        if ((a0 & a1 & a2 & a3) == 0x01010101u) return;
        __builtin_amdgcn_s_sleep(2);
    }
}
__device__ __forceinline__ float blo(unsigned u) { return __uint_as_float(u << 16); }
__device__ __forceinline__ float bhi(unsigned u) { return __uint_as_float(u & 0xffff0000u); }
__device__ __forceinline__ unsigned short f2bf(float f) {
    unsigned u = __float_as_uint(f);
    u += 0x7fffu + ((u >> 16) & 1u);
    return (unsigned short)(u >> 16);
}

// 4-batch dot: thread owns ONE col (kcol) and a k4 range; one weight float4 load
// feeds 4 batches (acc.x..acc.w = batches 0..3). Activation reads are wave-broadcast.
template<bool BF>
__device__ __forceinline__ float4 dotq(const void* wp, int cg, int kcol,
                                       int k4lo, int k4hi, const float* abase,
                                       int aoff, float4 acc) {
    if (BF) {
        const uint2* w = (const uint2*)wp + (size_t)cg*NK4*96 + kcol;
#pragma unroll 4
        for (int k4 = k4lo; k4 < k4hi; ++k4) {
            uint2 uu = w[(size_t)k4 * 96];
            float wx = blo(uu.x), wy = bhi(uu.x), wz = blo(uu.y), ww = bhi(uu.y);
            const float* ao = abase + (k4 - aoff)*4;
            float4 A0 = *(const float4*)(ao + 0*ASTR);
            float4 A1 = *(const float4*)(ao + 1*ASTR);
            float4 A2 = *(const float4*)(ao + 2*ASTR);
            float4 A3 = *(const float4*)(ao + 3*ASTR);
            acc.x = fmaf(wx, A0.x, acc.x); acc.x = fmaf(wy, A0.y, acc.x);
            acc.x = fmaf(wz, A0.z, acc.x); acc.x = fmaf(ww, A0.w, acc.x);
            acc.y = fmaf(wx, A1.x, acc.y); acc.y = fmaf(wy, A1.y, acc.y);
            acc.y = fmaf(wz, A1.z, acc.y); acc.y = fmaf(ww, A1.w, acc.y);
            acc.z = fmaf(wx, A2.x, acc.z); acc.z = fmaf(wy, A2.y, acc.z);
            acc.z = fmaf(wz, A2.z, acc.z); acc.z = fmaf(ww, A2.w, acc.z);
            acc.w = fmaf(wx, A3.x, acc.w); acc.w = fmaf(wy, A3.y, acc.w);
            acc.w = fmaf(wz, A3.z, acc.w); acc.w = fmaf(ww, A3.w, acc.w);
        }
    } else {
        const float4* w = (const float4*)wp + (size_t)cg*NK4*96 + kcol;
#pragma unroll 4
        for (int k4 = k4lo; k4 < k4hi; ++k4) {
            float4 wv = w[(size_t)k4 * 96];
            const float* ao = abase + (k4 - aoff)*4;
            float4 A0 = *(const float4*)(ao + 0*ASTR);
            float4 A1 = *(const float4*)(ao + 1*ASTR);
            float4 A2 = *(const float4*)(ao + 2*ASTR);
            float4 A3 = *(const float4*)(ao + 3*ASTR);
            acc.x = fmaf(wv.x, A0.x, acc.x); acc.x = fmaf(wv.y, A0.y, acc.x);
            acc.x = fmaf(wv.z, A0.z, acc.x); acc.x = fmaf(wv.w, A0.w, acc.x);
            acc.y = fmaf(wv.x, A1.x, acc.y); acc.y = fmaf(wv.y, A1.y, acc.y);
            acc.y = fmaf(wv.z, A1.z, acc.y); acc.y = fmaf(wv.w, A1.w, acc.y);
            acc.z = fmaf(wv.x, A2.x, acc.z); acc.z = fmaf(wv.y, A2.y, acc.z);
            acc.z = fmaf(wv.z, A2.z, acc.z); acc.z = fmaf(wv.w, A2.w, acc.z);
            acc.w = fmaf(wv.x, A3.x, acc.w); acc.w = fmaf(wv.y, A3.y, acc.w);
            acc.w = fmaf(wv.z, A3.z, acc.w); acc.w = fmaf(wv.w, A3.w, acc.w);
        }
    }
    return acc;
}

// ---------------- precompute kernels (unchanged) ----------------
__global__ void k_u(const float* __restrict__ w1, const float* __restrict__ w2,
                    float* __restrict__ u) {
    int e = blockIdx.x;
    int lane = threadIdx.x;
    float p = 0.f;
#pragma unroll
    for (int k = lane; k < DENC; k += 64) p += w1[e*DENC + k] * w2[k];
    p = wave_sum(p);
    if (lane == 0) u[e] = p;
}

__global__ void k_ectx(const float* __restrict__ C, const float* __restrict__ u,
                       float* __restrict__ ectx) {
    int r = blockIdx.x*4 + (threadIdx.x >> 6);
    int lane = threadIdx.x & 63;
    const float* row = C + (size_t)r*DENC;
    const float* vc  = u + HHH;
    float p = 0.f;
#pragma unroll
    for (int k = 0; k < DENC/64; ++k) p += row[lane + k*64] * vc[lane + k*64];
    p = wave_sum(p);
    if (lane == 0) ectx[r] = p;
}

template<bool BF>
__global__ void k_wpack(const float* __restrict__ Wx, const float* __restrict__ Wh,
                        void* __restrict__ wp) {
    int id = blockIdx.x*256 + threadIdx.x;
    int e = id & 3;
    int q = id >> 2;
    int col = q % 96;
    q /= 96;
    int k4 = q % NK4;
    int cg = q / NK4;
    int k = k4*4 + e;
    int j = (col >> 5)*512 + cg*32 + (col & 31);
    float v = (k < 768) ? Wx[(size_t)k*NG + j] : Wh[(size_t)(k-768)*NG + j];
    if (BF) ((unsigned short*)wp)[id] = f2bf(v);
    else    ((float*)wp)[id] = v;
}

// ---------------- main kernel ----------------
// 256 blocks = (bg = blk>>4) x (cg = blk&15): 4 batches x 96 cols (32 z, 32 r, 32 h).
// Attention role: b_att = blk>>2, ds = blk&3. Dot threads: ks=tid/96, kcol=tid%96.
template<bool BF>
__launch_bounds__(NTHR, 1)
__global__ void decoder(const float* __restrict__ inp, const float* __restrict__ C,
                        const float* __restrict__ bias, const void* __restrict__ wpv,
                        const float* __restrict__ u, float* __restrict__ ectx_g,
                        float* __restrict__ out, float* __restrict__ ws) {
    unsigned char* fl = (unsigned char*)ws;
    float* hG   = ws + OFF_HG;
    float* ctxG = ws + OFF_CTXG;
    float* rhG  = ws + OFF_RHG;
    float* hdP  = ws + OFF_HD;

    const int tid  = threadIdx.x;
    const int w    = tid >> 6;
    const int blk  = blockIdx.x;
    const int bg   = blk >> 4;
    const int cg   = blk & 15;
    const int b_att = blk >> 2;
    const int ds    = blk & 3;
    const int bl_att = cg >> 2;        // == b_att & 3
    const int ks   = tid / 96;
    const int kcol = tid - ks*96;
    const int sub  = kcol >> 5;
    const int q32k = kcol & 31;
    const int jpk  = cg*32 + q32k;

    __shared__ float sh_C[TENC*128];                 // 131 KB fp32 C slice [q][dp]
    __shared__ __align__(16) float sh_st[4*ASTR];    // staging [b][k]: x -> ctx -> rh
    __shared__ __align__(16) float sh_h[4*ASTR];     // h_prev [b][k]
    __shared__ __align__(16) float sh_part[1536];    // [ks][col][b] K-split partials
    __shared__ float sh_att[TENC];
    __shared__ float sh_ectx[TENC];
    __shared__ __align__(16) float sh_u[512];
    __shared__ float sh_z[128];                      // [q32][b]
    __shared__ float sh_cred[2][128];
    __shared__ float sh_red[4];
    __shared__ float sh_hdp[8];
    __shared__ float sh_scal;

    // one-time staging
    for (int i = tid; i < TENC*128; i += NTHR)
        sh_C[i] = C[((size_t)b_att*TENC + (i >> 7))*DENC + ds*128 + (i & 127)];
    if (tid < TENC) sh_ectx[tid] = ectx_g[b_att*TENC + tid];
    if (tid < 128) ((float4*)sh_u)[tid] = ((const float4*)(u))[tid];
    const float bias_c = bias[sub*512 + jpk];

    const int i0 = tid, i1 = tid + 384, i2 = tid + 768;

    for (int t = 0; t < TDEC; ++t) {
        // ----- stage x (4 batches), float4 coalesced -----
        __syncthreads();                                    // guard sh_st reuse
        if (tid < 256) {
            int bb = tid >> 6, k4i = tid & 63;
            *(float4*)&sh_st[bb*ASTR + k4i*4] =
                *(const float4*)&inp[((size_t)(bg*4 + bb)*TDEC + t)*DIN + k4i*4];
        }
        __syncthreads();

        // ----- x-part dots: k4 quarter of [0,64), all cols, 4 batches -----
        float4 acc = make_float4(ks == 0 ? bias_c : 0.f, ks == 0 ? bias_c : 0.f,
                                 ks == 0 ? bias_c : 0.f, ks == 0 ? bias_c : 0.f);
        acc = dotq<BF>(wpv, cg, kcol, ks*16, ks*16 + 16, sh_st, 0, acc);

        // ----- waitC(t-1) -----
        if (t > 0) {
            if (tid == 0) waitflags16((unsigned*)(fl + ((((t-1)*3 + 2)*16 + bg) << 4)));
            __syncthreads();
        }

        // ----- issue h_prev loads into registers (latency hides under softmax) -----
        float2 h0, h1, h2;
        if (t > 0) {
            h0 = ldA2(&hG[(size_t)(bg*4 + (i0 >> 8))*HHH + (i0 & 255)*2]);
            h1 = ldA2(&hG[(size_t)(bg*4 + (i1 >> 8))*HHH + (i1 & 255)*2]);
            if (i2 < 1024)
                h2 = ldA2(&hG[(size_t)(bg*4 + (i2 >> 8))*HHH + (i2 & 255)*2]);
        }

        // ----- hd from published partials (lanes 0..15 of wave 0) -----
        if (t > 0) {
            if (tid < 64) {
                float v = (tid < 16) ? ldAf(&hdP[(bg*16 + tid)*4 + bl_att]) : 0.f;
                v += __shfl_xor(v, 1, 64);
                v += __shfl_xor(v, 2, 64);
                v += __shfl_xor(v, 4, 64);
                v += __shfl_xor(v, 8, 64);
                if (tid == 0) sh_scal = v;
            }
        } else if (tid == 0) sh_scal = 0.f;
        __syncthreads();
        const float hd = sh_scal;

        // ----- attention softmax (threads 0..255, matched barriers) -----
        if (tid < TENC) {
            float e = fmaxf(hd + sh_ectx[tid], 0.f);
            float wm = wave_max(e);
            if ((tid & 63) == 0) sh_red[w] = wm;
            __syncthreads();
            float mx = fmaxf(fmaxf(sh_red[0], sh_red[1]), fmaxf(sh_red[2], sh_red[3]));
            float ex = __expf(e - mx);
            float wse = wave_sum(ex);
            __syncthreads();
            if ((tid & 63) == 0) sh_red[w] = wse;
            __syncthreads();
            float dn = sh_red[0] + sh_red[1] + sh_red[2] + sh_red[3];
            sh_att[tid] = ex / dn;
        } else {
            __syncthreads(); __syncthreads(); __syncthreads();
        }
        __syncthreads();

        // ----- commit h_prev registers to LDS (wait happens AFTER softmax hid it;
        //       before the ctx-publish drain so event A is never delayed by loads) -----
        if (t > 0) {
            *(float2*)&sh_h[(i0 >> 8)*ASTR + (i0 & 255)*2] = h0;
            *(float2*)&sh_h[(i1 >> 8)*ASTR + (i1 & 255)*2] = h1;
            if (i2 < 1024) *(float2*)&sh_h[(i2 >> 8)*ASTR + (i2 & 255)*2] = h2;
        } else {
            for (int i = tid; i < 1024; i += NTHR)
                *(float2*)&sh_h[(i >> 8)*ASTR + (i & 255)*2] = make_float2(0.f, 0.f);
        }

        // ----- ctx slice (b_att, ds) from LDS C; publish -----
        if (tid < TENC) {
            const int dp = tid & 127, hf = tid >> 7;
            const float* Cl = sh_C + (size_t)hf*128*128 + dp;
            float a = 0.f;
#pragma unroll 8
            for (int q = 0; q < 128; ++q)
                a = fmaf(sh_att[hf*128 + q], Cl[(size_t)q*128], a);
            sh_cred[hf][dp] = a;
        }
        __syncthreads();                                    // covers h commit + cred
        if (tid < 128) stA(&ctxG[(size_t)b_att*HHH + ds*128 + tid],
                           sh_cred[0][tid] + sh_cred[1][tid]);
        drain_stores();
        __syncthreads();
        if (tid == 0) setflag(fl + (((t*3 + 0)*16 + bg) << 4) + cg);   // event A

        // ----- h-part dots (z,r cols): quarter of [192,320) over h_prev -----
        if (t > 0 && kcol < 64)
            acc = dotq<BF>(wpv, cg, kcol, 192 + ks*32, 192 + ks*32 + 32, sh_h, 192, acc);

        // ----- wait A; stage ctx; ctx dots quarter of [64,192) -----
        if (tid == 0) waitflags16((unsigned*)(fl + (((t*3 + 0)*16 + bg) << 4)));
        __syncthreads();
        for (int i = tid; i < 1024; i += NTHR) {
            int bb = i >> 8, j2 = (i & 255)*2;
            float2 f = ldA2(&ctxG[(size_t)(bg*4 + bb)*HHH + j2]);
            *(float2*)&sh_st[bb*ASTR + j2] = f;
        }
        __syncthreads();
        acc = dotq<BF>(wpv, cg, kcol, 64 + ks*32, 64 + ks*32 + 32, sh_st, 64, acc);

        // ----- K-split merge for z/r; finish gates; publish rh -----
        __syncthreads();
        if (kcol < 64) *(float4*)&sh_part[(ks*96 + kcol)*4] = acc;
        __syncthreads();
        if (tid < 256) {
            int cz = tid >> 2, b = tid & 3;
            float s = sh_part[0*384 + cz*4 + b] + sh_part[1*384 + cz*4 + b]
                    + sh_part[2*384 + cz*4 + b] + sh_part[3*384 + cz*4 + b];
            if (cz < 32) {
                sh_z[cz*4 + b] = 1.f / (1.f + __expf(-s));
            } else {
                int jp = cg*32 + (cz - 32);
                float r = 1.f / (1.f + __expf(-s));
                stA(&rhG[(size_t)(bg*4 + b)*HHH + jp], r * sh_h[b*ASTR + jp]);
            }
        }
        drain_stores();
        __syncthreads();
        if (tid == 0) setflag(fl + (((t*3 + 1)*16 + bg) << 4) + cg);   // event B

        // ----- wait B; stage rh; rh dots (h cols); finish h -----
        if (tid == 0) waitflags16((unsigned*)(fl + (((t*3 + 1)*16 + bg) << 4)));
        __syncthreads();
        for (int i = tid; i < 1024; i += NTHR) {
            int bb = i >> 8, j2 = (i & 255)*2;
            float2 f = ldA2(&rhG[(size_t)(bg*4 + bb)*HHH + j2]);
            *(float2*)&sh_st[bb*ASTR + j2] = f;
        }
        __syncthreads();
        if (kcol >= 64) {
            acc = dotq<BF>(wpv, cg, kcol, 192 + ks*32, 192 + ks*32 + 32, sh_st, 192, acc);
            *(float4*)&sh_part[(ks*96 + kcol)*4] = acc;
        }
        __syncthreads();
        if (tid < 128) {
            int q32 = tid >> 2, b = tid & 3;
            int ch = 64 + q32;
            float s = sh_part[0*384 + ch*4 + b] + sh_part[1*384 + ch*4 + b]
                    + sh_part[2*384 + ch*4 + b] + sh_part[3*384 + ch*4 + b];
            int jp = cg*32 + q32;
            float hh = tanhf(s);
            float z  = sh_z[q32*4 + b];
            float hp = sh_h[b*ASTR + jp];
            float hn = z*hp + (1.f - z)*hh;
            stA(&hG[(size_t)(bg*4 + b)*HHH + jp], hn);
            out[((size_t)(bg*4 + b)*TDEC + t)*HHH + jp] = hn;
            // hdot partial: sum over q32 (lane bits 2..5) within each wave
            float p = sh_u[jp] * hn;
            p += __shfl_xor(p, 4, 64);
            p += __shfl_xor(p, 8, 64);
            p += __shfl_xor(p, 16, 64);
            p += __shfl_xor(p, 32, 64);
            if ((tid & 63) < 4) sh_hdp[(tid >> 6)*4 + (tid & 3)] = p;
        }
        __syncthreads();
        if (tid < 4) stA(&hdP[(bg*16 + cg)*4 + tid], sh_hdp[tid] + sh_hdp[4 + tid]);
        drain_stores();
        __syncthreads();
        if (tid == 0) setflag(fl + (((t*3 + 2)*16 + bg) << 4) + cg);   // event C
    }
}

extern "C" void kernel_launch(void* const* d_in, const int* in_sizes, int n_in,
                              void* d_out, int out_size, void* d_ws, size_t ws_size,
                              hipStream_t stream) {
    const float* inputs = (const float*)d_in[0];
    const float* C      = (const float*)d_in[1];
    const float* w1     = (const float*)d_in[2];
    const float* w2     = (const float*)d_in[3];
    const float* Wx     = (const float*)d_in[4];
    const float* Wh     = (const float*)d_in[5];
    const float* bias   = (const float*)d_in[6];
    float* out = (float*)d_out;
    float* ws  = (float*)d_ws;

    hipMemsetAsync(ws, 0, FLAGS_BYTES, stream);

    k_u   <<<1024, 64,  0, stream>>>(w1, w2, ws + OFF_U);
    k_ectx<<<(64*TENC)/4, 256, 0, stream>>>(C, ws + OFF_U, ws + OFF_ECTX);

    const size_t need_f32 = (size_t)(OFF_WP) * 4u + (size_t)WP_ELEMS * 4u;
    void* wp = (void*)(ws + OFF_WP);
    if (ws_size >= need_f32) {
        k_wpack<false><<<WP_ELEMS/256, 256, 0, stream>>>(Wx, Wh, wp);
        decoder<false><<<NBLK, NTHR, 0, stream>>>(inputs, C, bias, wp,
                                                  ws + OFF_U, ws + OFF_ECTX, out, ws);
    } else {
        k_wpack<true><<<WP_ELEMS/256, 256, 0, stream>>>(Wx, Wh, wp);
        decoder<true><<<NBLK, NTHR, 0, stream>>>(inputs, C, bias, wp,
                                                 ws + OFF_U, ws + OFF_ECTX, out, ws);
    }
}